// Round 4
// baseline (233.606 us; speedup 1.0000x reference)
//
#include <hip/hip_runtime.h>
#include <stdint.h>

// Problem constants (fixed by the reference file). All buffers are FLOAT32:
// round-3 evidence — a bit-exact bf16 pipeline still NaN'd, which only the
// "feats misread as u16" bug explains; the harness's "(bf16)" label refers to
// its bf16-quantized *reference/threshold*, not the buffer dtype.
#define NYv 496
#define NXv 432
#define Cv  64
#define Bv  4
#define PLANE (NYv * NXv)            // 214272 elements per (b,c) plane
#define NVEC (NXv / 4)               // 108 float4 vectors per row (16B each)
#define RPB 2                        // rows per gather block
#define ACTIVE (RPB * NVEC)          // 216 active lanes of 256
#define CSPLIT 4
#define CCHUNK (Cv / CSPLIT)         // 16 channels per gather block

// Canvas region R: the LAST 4 output f32 planes (b=3, c=60..63), viewed as
// int32. 4*PLANE cells == B*NY*NX cells exactly. Cell (b,y,x) at
// outw[OFF_R + b*PLANE + y*NX + x]. d_ws is NOT used.
#define OFF_R ((size_t)(3 * Cv + 60) * PLANE)

// K1: scatter pillar index i (int32) into the canvas region of d_out.
// Canvas pre-set to -1 (hipMemsetAsync 0xFF) so unoccupied cells read <0.
__global__ __launch_bounds__(256) void scatter_idx(const int4* __restrict__ coords,
                                                   int* __restrict__ outw, int n) {
    int i = blockIdx.x * 256 + threadIdx.x;
    if (i >= n) return;
    int4 c4 = coords[i];             // (b, z, y, x)
    outw[OFF_R + (size_t)c4.x * PLANE + c4.z * NXv + c4.w] = i;
}

__device__ __forceinline__ float4 pack4(const float* __restrict__ feats,
                                        const int* p, int c) {
    float4 f;
    f.x = (p[0] >= 0) ? feats[(size_t)p[0] * Cv + c] : 0.0f;
    f.y = (p[1] >= 0) ? feats[(size_t)p[1] * Cv + c] : 0.0f;
    f.z = (p[2] >= 0) ? feats[(size_t)p[2] * Cv + c] : 0.0f;
    f.w = (p[3] >= 0) ? feats[(size_t)p[3] * Cv + c] : 0.0f;
    return f;
}

// K3: main gather — every plane EXCEPT the 4 canvas planes (b=3, c>=60).
// Block = 2 canvas rows x one 16-channel chunk; each active thread (216/256)
// owns 4 consecutive x cells, keeps 4 pillar indices in registers (one int4
// load), and writes one coalesced float4 store per channel. A pillar's 256B
// f32 feature row stays hot in L1 across the c-loop. Reads R, never writes R.
__global__ __launch_bounds__(256) void gather_main(const float* __restrict__ feats,
                                                   float* __restrict__ out) {
    int lane = (int)threadIdx.x;
    if (lane >= ACTIVE) return;
    int r = lane / NVEC;             // 0..1
    int v = lane - r * NVEC;         // 0..107
    int g = blockIdx.x * RPB + r;    // 0..1983
    int b = g / NYv;
    int y = g - b * NYv;
    int c0 = blockIdx.y * CCHUNK;

    const int* cnv = (const int*)out + OFF_R + (size_t)b * PLANE + y * NXv + v * 4;
    int4 pi = *reinterpret_cast<const int4*>(cnv);
    int p[4] = {pi.x, pi.y, pi.z, pi.w};

    float* outp = out + ((size_t)(b * Cv + c0)) * PLANE + y * NXv + v * 4;
    for (int c = 0; c < CCHUNK; ++c) {
        if (b == 3 && c0 + c >= 60) break;     // canvas planes: K4a/K4b handle
        *reinterpret_cast<float4*>(outp + (size_t)c * PLANE) = pack4(feats, p, c0 + c);
    }
}

// K4a: planes (b=3, c=60..62). Reads canvas b=3 (plane 255), writes planes
// 252..254 — disjoint; runs after K3 (stream order).
__global__ __launch_bounds__(256) void gather_tail3(const float* __restrict__ feats,
                                                    float* __restrict__ out) {
    int lane = (int)threadIdx.x;
    if (lane >= ACTIVE) return;
    int r = lane / NVEC;
    int v = lane - r * NVEC;
    int y = blockIdx.x * RPB + r;    // 0..495
    int j = blockIdx.y;              // 0..2 -> channel 60+j

    const int* cnv = (const int*)out + OFF_R + (size_t)3 * PLANE + y * NXv + v * 4;
    int4 pi = *reinterpret_cast<const int4*>(cnv);
    int p[4] = {pi.x, pi.y, pi.z, pi.w};

    float* outp = out + OFF_R + (size_t)j * PLANE + y * NXv + v * 4;
    *reinterpret_cast<float4*>(outp) = pack4(feats, p, 60 + j);
}

// K4b: plane (b=3, c=63) — the canvas-b=3 plane itself. Each thread reads its
// own 4 cells (int4) then overwrites exactly those 16 bytes (thread-local RAW,
// no cross-thread hazard). Runs after K4a (stream order protects K4a's reads).
__global__ __launch_bounds__(256) void gather_tail_last(const float* __restrict__ feats,
                                                        float* __restrict__ out) {
    int lane = (int)threadIdx.x;
    if (lane >= ACTIVE) return;
    int r = lane / NVEC;
    int v = lane - r * NVEC;
    int y = blockIdx.x * RPB + r;    // 0..495

    float* cellf = out + OFF_R + (size_t)3 * PLANE + y * NXv + v * 4;
    int4 pi = *reinterpret_cast<const int4*>(cellf);
    int p[4] = {pi.x, pi.y, pi.z, pi.w};
    *reinterpret_cast<float4*>(cellf) = pack4(feats, p, 63);
}

extern "C" void kernel_launch(void* const* d_in, const int* in_sizes, int n_in,
                              void* d_out, int out_size, void* d_ws, size_t ws_size,
                              hipStream_t stream) {
    const float* feats  = (const float*)d_in[0];   // f32, [N, 64]
    const int*   coords = (const int*)d_in[1];     // int32, [N, 4]
    int n = in_sizes[0] / Cv;                      // 48000 pillars
    float* out = (float*)d_out;
    int*   outw = (int*)d_out;

    // -1 sentinel across the canvas region (inside d_out; no d_ws use).
    hipMemsetAsync(outw + OFF_R, 0xFF, (size_t)Bv * PLANE * sizeof(int), stream);

    scatter_idx<<<(n + 255) / 256, 256, 0, stream>>>((const int4*)coords, outw, n);

    dim3 gmain((Bv * NYv) / RPB, CSPLIT);          // (992, 4)
    gather_main<<<gmain, 256, 0, stream>>>(feats, out);

    dim3 gtail(NYv / RPB, 3);                      // (248, 3)
    gather_tail3<<<gtail, 256, 0, stream>>>(feats, out);

    gather_tail_last<<<NYv / RPB, 256, 0, stream>>>(feats, out);
}

// Round 5
// 231.050 us; speedup vs baseline: 1.0111x; 1.0111x over previous
//
#include <hip/hip_runtime.h>
#include <stdint.h>

// All buffers f32 (round-4 evidence: bit-exact f32 pipeline passed, absmax 0).
// d_ws is ~877 MB (round-4 rocprof: per-iteration 857088 KB poison fills) —
// ample for the 3.4 MB index canvas, so the canvas lives in d_ws again and the
// gather covers all 256 output planes in ONE kernel (no tail dispatches).
#define NYv 496
#define NXv 432
#define Cv  64
#define Bv  4
#define PLANE (NYv * NXv)            // 214272 elements per (b,c) plane
#define NVEC (NXv / 4)               // 108 float4 vectors per row (16B each)
#define RPB 2                        // canvas rows per gather block
#define ACTIVE (RPB * NVEC)          // 216 active lanes of 256
#define CSPLIT 4
#define CCHUNK (Cv / CSPLIT)         // 16 channels per gather block

// K1: scatter pillar index i into canvas[(b*NY + y)*NX + x].
// Canvas pre-set to -1 (memset 0xFF) so unoccupied cells read <0.
__global__ __launch_bounds__(256) void scatter_idx(const int4* __restrict__ coords,
                                                   int* __restrict__ canvas, int n) {
    int i = blockIdx.x * 256 + threadIdx.x;
    if (i >= n) return;
    int4 c4 = coords[i];             // (b, z, y, x)
    canvas[((size_t)c4.x * NYv + c4.z) * NXv + c4.w] = i;
}

__device__ __forceinline__ float4 pack4(const float* __restrict__ feats,
                                        const int* p, int c) {
    float4 f;
    f.x = (p[0] >= 0) ? feats[(size_t)p[0] * Cv + c] : 0.0f;
    f.y = (p[1] >= 0) ? feats[(size_t)p[1] * Cv + c] : 0.0f;
    f.z = (p[2] >= 0) ? feats[(size_t)p[2] * Cv + c] : 0.0f;
    f.w = (p[3] >= 0) ? feats[(size_t)p[3] * Cv + c] : 0.0f;
    return f;
}

// K2: inverse gather over ALL planes. Block = 2 canvas rows x one 16-channel
// chunk; each active thread (216/256) owns 4 consecutive x cells, loads its 4
// pillar indices with one int4, then writes one coalesced float4 store per
// channel. unroll-4 keeps 4 independent masked-load+store groups in flight.
// A pillar's 16-channel chunk (64B, one cache line) stays hot in L1 across
// the thread's c-loop; only ~5.6% of cells are occupied, so feature loads are
// rare and the kernel is store-BW-bound.
__global__ __launch_bounds__(256) void gather_all(const float* __restrict__ feats,
                                                  const int* __restrict__ canvas,
                                                  float* __restrict__ out) {
    int lane = (int)threadIdx.x;
    if (lane >= ACTIVE) return;
    int r = lane / NVEC;             // 0..1
    int v = lane - r * NVEC;         // 0..107
    int g = blockIdx.x * RPB + r;    // 0..1983 (496%2==0: blocks never straddle b)
    int b = g / NYv;
    int y = g - b * NYv;
    int c0 = blockIdx.y * CCHUNK;

    int4 pi = *reinterpret_cast<const int4*>(canvas + (size_t)g * NXv + v * 4);
    int p[4] = {pi.x, pi.y, pi.z, pi.w};

    float* outp = out + ((size_t)(b * Cv + c0)) * PLANE + y * NXv + v * 4;
#pragma unroll 4
    for (int c = 0; c < CCHUNK; ++c) {
        *reinterpret_cast<float4*>(outp + (size_t)c * PLANE) = pack4(feats, p, c0 + c);
    }
}

extern "C" void kernel_launch(void* const* d_in, const int* in_sizes, int n_in,
                              void* d_out, int out_size, void* d_ws, size_t ws_size,
                              hipStream_t stream) {
    const float* feats  = (const float*)d_in[0];   // f32, [N, 64]
    const int*   coords = (const int*)d_in[1];     // int32, [N, 4]
    int n = in_sizes[0] / Cv;                      // 48000 pillars
    float* out    = (float*)d_out;
    int*   canvas = (int*)d_ws;                    // 3.43 MB of ~877 MB ws

    // -1 sentinel (0xAA poison is also negative, but don't rely on it).
    hipMemsetAsync(canvas, 0xFF, (size_t)Bv * PLANE * sizeof(int), stream);

    scatter_idx<<<(n + 255) / 256, 256, 0, stream>>>((const int4*)coords, canvas, n);

    dim3 gmain((Bv * NYv) / RPB, CSPLIT);          // (992, 4) = 3968 blocks
    gather_all<<<gmain, 256, 0, stream>>>(feats, canvas, out);
}